// Round 3
// baseline (1191.976 us; speedup 1.0000x reference)
//
#include <hip/hip_runtime.h>
#include <stdint.h>

typedef __bf16 bf16;
typedef __bf16 bf16x8 __attribute__((ext_vector_type(8)));
typedef float f32x4 __attribute__((ext_vector_type(4)));

#define DEV __device__ __forceinline__

static constexpr int Dm   = 1024;
static constexpr int DFFm = 4096;
static constexpr int Tm   = 2048;   // B*S tokens
static constexpr int Vm   = 32000;

// ---------------- helpers ----------------
#define GLOAD_LDS16(g, l)                                                      \
  __builtin_amdgcn_global_load_lds(                                            \
      (const __attribute__((address_space(1))) unsigned int*)(g),              \
      (__attribute__((address_space(3))) unsigned int*)(l), 16, 0, 0)

DEV float gelu_fast(float v) {  // tanh-approx gelu, fast exp (expert path)
  float u = 0.7978845608028654f * (v + 0.044715f * v * v * v);
  float e = __expf(2.0f * u);
  float t = 1.0f - 2.0f / (e + 1.0f);
  return 0.5f * v * (1.0f + t);
}
DEV float gelu_precise(float v) {  // temporal path feeds router: use tanhf
  float u = 0.7978845608028654f * (v + 0.044715f * v * v * v);
  return 0.5f * v * (1.0f + tanhf(u));
}

// ---------------- GEMM: C = A[M][K] * B^T ([N][K]) ----------------
// Augmented-K fp32-ish accuracy: A'=[Ah|Al|Ah], B'=[Bh|Bh|Bl] -> hh+lh+hl.
enum { EPI_GELU_SPLIT = 0, EPI_RESID = 1, EPI_GELU_BF16 = 2, EPI_MOE = 3, EPI_BIAS = 4 };

struct GemmP {
  const bf16* Ah;
  const bf16* Bh;
  const float* bias;
  const float* rwp;     // routing weights [T][8]
  const int* cnt;       // per-expert token counts [8]
  const int* idx;       // per-expert token lists [8][2048]
  float* outF;
  bf16* outH;
  int K; int N;
  int lda; int ldb; int ldo;   // element strides (lda/ldb may exceed K for split-K)
  long aBS, bBS, outBS;        // per-z strides (experts: batch; split-K: k-chunk)
  int biasBS;
  int ebase;                   // global expert base for this dispatch's z=0
};

template <int EPI, bool GATHER, bool SWZ>
__launch_bounds__(256, 2)
__global__ void gemm_bt(GemmP p) {
  constexpr bool SPARSE = GATHER || (EPI == EPI_MOE);
  __shared__ bf16 lds[8192];          // A tile 128x32 | B tile 128x32
  bf16* ldsA = lds;
  bf16* ldsB = lds + 4096;

  const int tid  = threadIdx.x;
  const int lane = tid & 63;
  const int wid  = tid >> 6;
  const int wr   = wid >> 1;   // 2x2 wave grid, each wave owns 64x64
  const int wc   = wid & 1;
  const int z    = blockIdx.z;

  int bx = blockIdx.x, by = blockIdx.y;
  if constexpr (SWZ) {
    // physical dispatch order is x-fastest; xcd = lin & 7 (8 XCDs, round-robin).
    // remap so each XCD owns a contiguous panel-major chunk (B-panel L2 reuse).
    const int gx = gridDim.x, gy = gridDim.y;
    const int nwg = gx * gy;
    const int lin = by * gx + bx;
    const int q = nwg >> 3, r = nwg & 7;
    const int xcd = lin & 7, loc = lin >> 3;
    const int nid = (xcd < r ? xcd * (q + 1) : r * (q + 1) + (xcd - r) * q) + loc;
    bx = nid / gy; by = nid % gy;   // consecutive nid share bx (same B panel)
  }

  const long am0 = (long)by * 128;
  const long bn0 = (long)bx * 128;

  int cntE = 0;
  const int* il = nullptr;
  if constexpr (SPARSE) {
    cntE = p.cnt[p.ebase + z];
    if (am0 >= cntE) return;  // wave-uniform early exit (before any barrier)
    il = p.idx + (long)(p.ebase + z) * 2048;
  }

  const long lda = p.lda, ldb = p.ldb;
  const long K = p.K;

  // per-thread staging sources: chunk c covers row (c>>2), 16B piece (c&3)
  const int c0 = wid * 64 + lane;
  const int c1 = 256 + wid * 64 + lane;
  const bf16 *aS0, *aS1, *bS0, *bS1;
  {
    const bf16* Bb = p.Bh + (long)z * p.bBS + bn0 * ldb;
    bS0 = Bb + (long)(c0 >> 2) * ldb + (c0 & 3) * 8;
    bS1 = Bb + (long)(c1 >> 2) * ldb + (c1 & 3) * 8;
    if constexpr (GATHER) {
      const int g0 = (int)am0 + (c0 >> 2);
      const int g1 = (int)am0 + (c1 >> 2);
      const long r0 = il[g0 < cntE ? g0 : 0];
      const long r1 = il[g1 < cntE ? g1 : 0];
      aS0 = p.Ah + r0 * lda + (c0 & 3) * 8;
      aS1 = p.Ah + r1 * lda + (c1 & 3) * 8;
    } else {
      const bf16* Ab = p.Ah + (long)z * p.aBS + am0 * lda;
      aS0 = Ab + (long)(c0 >> 2) * lda + (c0 & 3) * 8;
      aS1 = Ab + (long)(c1 >> 2) * lda + (c1 & 3) * 8;
    }
  }
  char* dst0 = (char*)(void*)lds + (wid * 64) * 16;        // + lane*16 by HW
  char* dst1 = (char*)(void*)lds + (256 + wid * 64) * 16;

  f32x4 acc[4][4] = {};

  const int aoff = (wr * 64 + (lane & 15)) * 32 + (lane >> 4) * 8;
  const int boff = (wc * 64 + (lane & 15)) * 32 + (lane >> 4) * 8;

  for (long k0 = 0; k0 < K; k0 += 32) {
    __syncthreads();
    GLOAD_LDS16(aS0 + k0, dst0);
    GLOAD_LDS16(aS1 + k0, dst1);
    GLOAD_LDS16(bS0 + k0, dst0 + 8192);
    GLOAD_LDS16(bS1 + k0, dst1 + 8192);
    __syncthreads();

    bf16x8 a[4], b[4];
#pragma unroll
    for (int m = 0; m < 4; ++m) a[m] = *(const bf16x8*)(ldsA + aoff + m * 512);
#pragma unroll
    for (int n = 0; n < 4; ++n) b[n] = *(const bf16x8*)(ldsB + boff + n * 512);
#pragma unroll
    for (int m = 0; m < 4; ++m)
#pragma unroll
      for (int n = 0; n < 4; ++n)
        acc[m][n] = __builtin_amdgcn_mfma_f32_16x16x32_bf16(a[m], b[n], acc[m][n], 0, 0, 0);
  }

  const long N = p.N;

#pragma unroll
  for (int m = 0; m < 4; ++m) {
#pragma unroll
    for (int n = 0; n < 4; ++n) {
      const long col = bn0 + wc * 64 + n * 16 + (lane & 15);
      float bv;
      if constexpr (EPI == EPI_RESID) bv = (z == 0) ? p.bias[col] : 0.0f;
      else bv = p.bias[(long)z * p.biasBS + col];
#pragma unroll
      for (int r = 0; r < 4; ++r) {
        const long row = am0 + wr * 64 + m * 16 + (lane >> 4) * 4 + r;
        float v = acc[m][n][r] + bv;
        if constexpr (EPI == EPI_GELU_SPLIT) {
          // write augmented A' row for the next GEMM: [h | l | h], row stride ldo=3N
          float g = gelu_precise(v);
          bf16 h = (bf16)g;
          long o = row * (long)p.ldo + col;
          p.outH[o] = h;
          p.outH[o + N] = (bf16)(g - (float)h);
          p.outH[o + 2 * N] = h;
        } else if constexpr (EPI == EPI_RESID) {
          // split-K: both z-chunks accumulate into X (which pre-holds resid)
          atomicAdd(p.outF + row * N + col, v);
        } else if constexpr (EPI == EPI_GELU_BF16) {
          long o = (long)z * p.outBS + row * N + col;
          p.outH[o] = (bf16)gelu_fast(v);
        } else if constexpr (EPI == EPI_MOE) {
          if (row < cntE) {
            const int tok = il[row];
            const float wgt = p.rwp[(long)tok * 8 + p.ebase + z];
            atomicAdd(p.outF + (long)tok * N + col, wgt * v);
          }
        } else {  // EPI_BIAS: streaming fp32 logits, bypass L3 (protect WLT)
          __builtin_nontemporal_store(v, p.outF + row * N + col);
        }
      }
    }
  }
}

// ------- transpose fp32 [R][C] -> bf16 [C][R] (AUG: [C][3R] = [h|h|l]) -------
template <bool AUG>
__global__ void transpose_cvt(const float* __restrict__ in, bf16* __restrict__ out,
                              int R, int C, long inBS, long outBS) {
  __shared__ float tile[32][33];
  const float* inp = in + (long)blockIdx.z * inBS;
  const long c0 = (long)blockIdx.x * 32;
  const long r0 = (long)blockIdx.y * 32;
  const int tx = threadIdx.x;  // 32
  const int ty = threadIdx.y;  // 8
#pragma unroll
  for (int i = 0; i < 4; ++i) {
    int r = ty + i * 8;
    tile[r][tx] = inp[(r0 + r) * (long)C + c0 + tx];
  }
  __syncthreads();
  const long ob = (long)blockIdx.z * outBS;
  const long stride = AUG ? 3L * R : (long)R;
#pragma unroll
  for (int i = 0; i < 4; ++i) {
    int c = ty + i * 8;
    float v = tile[tx][c];
    bf16 h = (bf16)v;
    long o = ob + (c0 + c) * stride + r0 + tx;
    out[o] = h;
    if constexpr (AUG) {
      out[o + R] = h;
      out[o + 2 * R] = (bf16)(v - (float)h);
    }
  }
}

// ------------- embedding gather -------------
__global__ void embed_kernel(const int* __restrict__ ids, const float* __restrict__ emb,
                             float* __restrict__ x) {
  const long t = blockIdx.x;
  const int id = ids[t];
  ((float4*)(x + t * 1024))[threadIdx.x] = ((const float4*)(emb + (long)id * 1024))[threadIdx.x];
}

// ------------- LayerNorm -> augmented bf16 [h|l|h] row (stride 3072) -------------
__global__ void ln_aug_kernel(const float* __restrict__ x, const float* __restrict__ sc,
                              const float* __restrict__ bi, bf16* __restrict__ oa) {
  const long t = blockIdx.x;
  const int tid = threadIdx.x;  // 256
  const int lane = tid & 63, wid = tid >> 6;
  float4 a = ((const float4*)(x + t * 1024))[tid];
  float s = a.x + a.y + a.z + a.w;
  float q = a.x * a.x + a.y * a.y + a.z * a.z + a.w * a.w;
#pragma unroll
  for (int off = 32; off; off >>= 1) {
    s += __shfl_down(s, off);
    q += __shfl_down(q, off);
  }
  __shared__ float sr[4], qr[4];
  if (lane == 0) { sr[wid] = s; qr[wid] = q; }
  __syncthreads();
  s = sr[0] + sr[1] + sr[2] + sr[3];
  q = qr[0] + qr[1] + qr[2] + qr[3];
  const float mu = s * (1.0f / 1024.0f);
  const float var = q * (1.0f / 1024.0f) - mu * mu;
  const float rs = rsqrtf(var + 1e-5f);
#pragma unroll
  for (int j = 0; j < 4; ++j) {
    const int d = tid * 4 + j;
    const float g = (((const float*)&a)[j] - mu) * rs * sc[d] + bi[d];
    const bf16 h = (bf16)g;
    oa[t * 3072 + d] = h;
    oa[t * 3072 + 1024 + d] = (bf16)(g - (float)h);
    oa[t * 3072 + 2048 + d] = h;
  }
}

// ------------- router: logits, top-2 softmax, scatter + top2 record -------------
__global__ void router_kernel(const float* __restrict__ x, const float* __restrict__ Wr,
                              const float* __restrict__ br, float* __restrict__ rwo,
                              int* __restrict__ top2) {
  const long t = blockIdx.x;
  const int lane = threadIdx.x;  // 64
  float acc[8];
#pragma unroll
  for (int e = 0; e < 8; ++e) acc[e] = 0.0f;
  const float4* xr = (const float4*)(x + t * 1024);
#pragma unroll
  for (int j = 0; j < 4; ++j) {
    const int d4 = j * 64 + lane;
    float4 xv = xr[d4];
#pragma unroll
    for (int u = 0; u < 4; ++u) {
      const float xs = ((const float*)&xv)[u];
      const float4* wp = (const float4*)(Wr + (long)(d4 * 4 + u) * 8);
      float4 w0 = wp[0], w1 = wp[1];
      acc[0] += xs * w0.x; acc[1] += xs * w0.y; acc[2] += xs * w0.z; acc[3] += xs * w0.w;
      acc[4] += xs * w1.x; acc[5] += xs * w1.y; acc[6] += xs * w1.z; acc[7] += xs * w1.w;
    }
  }
#pragma unroll
  for (int off = 32; off; off >>= 1)
#pragma unroll
    for (int e = 0; e < 8; ++e) acc[e] += __shfl_down(acc[e], off);
  if (lane == 0) {
    float v[8];
#pragma unroll
    for (int e = 0; e < 8; ++e) v[e] = acc[e] + br[e];
    int i0 = 0; float v0 = v[0];
    for (int e = 1; e < 8; ++e) if (v[e] > v0) { v0 = v[e]; i0 = e; }
    int i1 = -1; float v1 = -3.4e38f;
    for (int e = 0; e < 8; ++e) if (e != i0 && v[e] > v1) { v1 = v[e]; i1 = e; }
    float e1 = expf(v1 - v0);
    float den = 1.0f + e1;
    float w0 = 1.0f / den, w1 = e1 / den;
    float* o = rwo + t * 8;
#pragma unroll
    for (int e = 0; e < 8; ++e) o[e] = (e == i0) ? w0 : (e == i1 ? w1 : 0.0f);
    top2[t] = i0 | (i1 << 8);
  }
}

// ------------- per-expert token list build (order-free; outputs order-invariant) ------
__global__ void build_lists(const int* __restrict__ top2, int* __restrict__ cnt,
                            int* __restrict__ idx) {
  const int t = blockIdx.x * 256 + threadIdx.x;
  const int rec = top2[t];
  const int e0 = rec & 255, e1 = (rec >> 8) & 255;
  int p0 = atomicAdd(&cnt[e0], 1);
  idx[e0 * 2048 + p0] = t;
  int p1 = atomicAdd(&cnt[e1], 1);
  idx[e1 * 2048 + p1] = t;
}

// ------------- fp32 -> bf16 flat convert -------------
__global__ void cvt_bf16_kernel(const float* __restrict__ in, bf16* __restrict__ out, long n) {
  long i = ((long)blockIdx.x * blockDim.x + threadIdx.x) * 8;
  if (i >= n) return;
  float4 a = *(const float4*)(in + i);
  float4 b = *(const float4*)(in + i + 4);
  bf16x8 o;
  o[0] = (bf16)a.x; o[1] = (bf16)a.y; o[2] = (bf16)a.z; o[3] = (bf16)a.w;
  o[4] = (bf16)b.x; o[5] = (bf16)b.y; o[6] = (bf16)b.z; o[7] = (bf16)b.w;
  *(bf16x8*)(out + i) = o;
}

// ---------------- host launch ----------------
extern "C" void kernel_launch(void* const* d_in, const int* in_sizes, int n_in,
                              void* d_out, int out_size, void* d_ws, size_t ws_size,
                              hipStream_t stream) {
  (void)in_sizes; (void)n_in; (void)out_size; (void)ws_size;
  const int*   ids  = (const int*)d_in[0];
  const float* emb  = (const float*)d_in[1];
  const float* tlns = (const float*)d_in[2];
  const float* tlnb = (const float*)d_in[3];
  const float* tw1  = (const float*)d_in[4];
  const float* tb1  = (const float*)d_in[5];
  const float* tw2  = (const float*)d_in[6];
  const float* tb2  = (const float*)d_in[7];
  const float* Wr   = (const float*)d_in[8];
  const float* br   = (const float*)d_in[9];
  const float* ew1  = (const float*)d_in[10];
  const float* eb1  = (const float*)d_in[11];
  const float* ew2  = (const float*)d_in[12];
  const float* eb2  = (const float*)d_in[13];
  const float* Wl   = (const float*)d_in[14];
  const float* bl   = (const float*)d_in[15];

  float* logits = (float*)d_out;
  float* rwout  = (float*)d_out + (long)Tm * Vm;

  // ws arena (~160 MiB) with phase-based region reuse
  size_t off = 0;
  auto take = [&](size_t bytes) {
    void* pp = (char*)d_ws + off;
    off += (bytes + 255) & ~(size_t)255;
    return pp;
  };
  float* X    = (float*)take((size_t)Tm * Dm * 4);
  bf16*  XB   = (bf16*) take((size_t)Tm * Dm * 2);
  float* Y    = (float*)take((size_t)Tm * Dm * 4);
  bf16*  YB   = (bf16*) take((size_t)Tm * Dm * 2);
  int*   top2 = (int*)  take((size_t)Tm * 4);
  int*   cnt  = (int*)  take(8 * 4);
  int*   idxl = (int*)  take((size_t)8 * Tm * 4);
  char*  S    = (char*) take(134217728);   // 128 MiB phase-shared scratch

  // temporal phase
  bf16* A1  = (bf16*)S;                              // [2048][3072]  12.6 MB
  bf16* W1A = (bf16*)(S + 12582912);                 // [4096][3072]  25.2 MB
  bf16* W2A = (bf16*)(S + 12582912 + 25165824);      // [1024][12288] 25.2 MB
  bf16* HTA = (bf16*)(S + 12582912 + 2 * 25165824);  // [2048][12288] 50.3 MB (end 113.2)
  // expert phase
  bf16* EW1T = (bf16*)S;                             // 4x[4096][1024] 33.6 MB
  bf16* HE   = (bf16*)(S + 33554432);                // 4x[2048][4096] 67.1 MB (end 100.7)
  bf16* EW2T = (bf16*)(S + 100663296);               // 4x[1024][4096] 33.6 MB (end 134.2)
  // logits phase
  bf16* WLT  = (bf16*)S;                             // [32000][1024]  65.5 MB

  embed_kernel<<<dim3(Tm), dim3(256), 0, stream>>>(ids, emb, X);

  // ---- temporal residual MLP blocks: augmented-K plain GEMMs ----
  for (int l = 0; l < 2; ++l) {
    transpose_cvt<true><<<dim3(DFFm / 32, Dm / 32, 1), dim3(32, 8), 0, stream>>>(
        tw1 + (long)l * Dm * DFFm, W1A, Dm, DFFm, 0, 0);
    transpose_cvt<true><<<dim3(Dm / 32, DFFm / 32, 1), dim3(32, 8), 0, stream>>>(
        tw2 + (long)l * DFFm * Dm, W2A, DFFm, Dm, 0, 0);
    ln_aug_kernel<<<dim3(Tm), dim3(256), 0, stream>>>(X, tlns + l * Dm, tlnb + l * Dm, A1);

    GemmP p1{};
    p1.Ah = A1; p1.Bh = W1A;
    p1.bias = tb1 + (long)l * DFFm;
    p1.outH = HTA;
    p1.K = 3072; p1.N = DFFm; p1.lda = 3072; p1.ldb = 3072; p1.ldo = 3 * DFFm;
    gemm_bt<EPI_GELU_SPLIT, false, true>
        <<<dim3(DFFm / 128, Tm / 128, 1), dim3(256), 0, stream>>>(p1);

    GemmP p2{};
    p2.Ah = HTA; p2.Bh = W2A;
    p2.bias = tb2 + (long)l * Dm;
    p2.outF = X;                         // X pre-holds residual; both z-chunks atomicAdd
    p2.K = 6144; p2.N = Dm; p2.lda = 12288; p2.ldb = 12288;
    p2.aBS = 6144; p2.bBS = 6144;        // split-K chunk offsets
    gemm_bt<EPI_RESID, false, true>
        <<<dim3(Dm / 128, Tm / 128, 2), dim3(256), 0, stream>>>(p2);
  }

  // ---- router (fp32) + token lists ----
  router_kernel<<<dim3(Tm), dim3(64), 0, stream>>>(X, Wr, br, rwout, top2);
  hipMemsetAsync(cnt, 0, 8 * 4, stream);
  build_lists<<<dim3(Tm / 256), dim3(256), 0, stream>>>(top2, cnt, idxl);
  cvt_bf16_kernel<<<dim3(Tm * Dm / (256 * 8)), dim3(256), 0, stream>>>(X, XB, (long)Tm * Dm);
  hipMemsetAsync(Y, 0, (size_t)Tm * Dm * 4, stream);

  // ---- sparse top-2 expert stack, 2 quads of 4 experts (bf16) ----
  for (int q = 0; q < 2; ++q) {
    transpose_cvt<false><<<dim3(DFFm / 32, Dm / 32, 4), dim3(32, 8), 0, stream>>>(
        ew1 + (long)q * 4 * Dm * DFFm, EW1T, Dm, DFFm, (long)Dm * DFFm, (long)DFFm * Dm);
    transpose_cvt<false><<<dim3(Dm / 32, DFFm / 32, 4), dim3(32, 8), 0, stream>>>(
        ew2 + (long)q * 4 * DFFm * Dm, EW2T, DFFm, Dm, (long)DFFm * Dm, (long)Dm * DFFm);

    GemmP pe1{};
    pe1.Ah = XB; pe1.Bh = EW1T;
    pe1.bias = eb1 + (long)q * 4 * DFFm; pe1.biasBS = DFFm;
    pe1.outH = HE; pe1.outBS = (long)Tm * DFFm;
    pe1.aBS = 0; pe1.bBS = (long)DFFm * Dm;
    pe1.cnt = cnt; pe1.idx = idxl; pe1.ebase = q * 4;
    pe1.K = Dm; pe1.N = DFFm; pe1.lda = Dm; pe1.ldb = Dm;
    gemm_bt<EPI_GELU_BF16, true, true>
        <<<dim3(DFFm / 128, Tm / 128, 4), dim3(256), 0, stream>>>(pe1);

    GemmP pe2{};
    pe2.Ah = HE; pe2.aBS = (long)Tm * DFFm;
    pe2.Bh = EW2T; pe2.bBS = (long)Dm * DFFm;
    pe2.bias = eb2 + (long)q * 4 * Dm; pe2.biasBS = Dm;
    pe2.rwp = rwout; pe2.cnt = cnt; pe2.idx = idxl; pe2.ebase = q * 4;
    pe2.outF = Y;
    pe2.K = DFFm; pe2.N = Dm; pe2.lda = DFFm; pe2.ldb = DFFm;
    gemm_bt<EPI_MOE, false, true>
        <<<dim3(Dm / 128, Tm / 128, 4), dim3(256), 0, stream>>>(pe2);
  }

  // ---- final logits GEMM ----
  cvt_bf16_kernel<<<dim3(Tm * Dm / (256 * 8)), dim3(256), 0, stream>>>(Y, YB, (long)Tm * Dm);
  transpose_cvt<false><<<dim3(Vm / 32, Dm / 32, 1), dim3(32, 8), 0, stream>>>(
      Wl, WLT, Dm, Vm, 0, 0);
  GemmP pl{};
  pl.Ah = YB; pl.Bh = WLT; pl.bias = bl;
  pl.outF = logits;
  pl.K = Dm; pl.N = Vm; pl.lda = Dm; pl.ldb = Dm;
  gemm_bt<EPI_BIAS, false, true>
      <<<dim3(Vm / 128, Tm / 128, 1), dim3(256), 0, stream>>>(pl);
}

// Round 4
// 1006.790 us; speedup vs baseline: 1.1839x; 1.1839x over previous
//
#include <hip/hip_runtime.h>
#include <stdint.h>

typedef __bf16 bf16;
typedef __bf16 bf16x8 __attribute__((ext_vector_type(8)));
typedef float f32x4 __attribute__((ext_vector_type(4)));

#define DEV __device__ __forceinline__

static constexpr int Dm   = 1024;
static constexpr int DFFm = 4096;
static constexpr int Tm   = 2048;   // B*S tokens
static constexpr int Vm   = 32000;

// ---------------- helpers ----------------
#define GLOAD_LDS16(g, l)                                                      \
  __builtin_amdgcn_global_load_lds(                                            \
      (const __attribute__((address_space(1))) unsigned int*)(g),              \
      (__attribute__((address_space(3))) unsigned int*)(l), 16, 0, 0)

DEV float gelu_tanh(float v) {  // matches jax.nn.gelu (approximate=True)
  float u = 0.7978845608028654f * (v + 0.044715f * v * v * v);
  float e = __expf(2.0f * u);
  float t = 1.0f - 2.0f / (e + 1.0f);
  return 0.5f * v * (1.0f + t);
}

// ---------------- GEMM: C = A[M][K] * B^T ([N][K]) ----------------
// Augmented-K fp32-ish accuracy: A'=[Ah|Al|Ah], B'=[Bh|Bh|Bl] -> hh+lh+hl.
// BK=64, XOR-swizzled LDS (chunk ^= row&7) with pre-swizzled global source.
enum { EPI_GELU_SPLIT = 0, EPI_RESID = 1, EPI_GELU_BF16 = 2, EPI_MOE = 3, EPI_BIAS = 4 };

struct GemmP {
  const bf16* Ah;
  const bf16* Bh;
  const float* bias;
  const float* rwp;     // routing weights [T][8]
  const int* cnt;       // per-expert token counts [8]
  const int* idx;       // per-expert token lists [8][2048]
  float* outF;
  bf16* outH;
  int K; int N;
  int lda; int ldb; int ldo;
  long aBS, bBS, outBS;        // per-ze strides
  int biasBS;
  int ebase;                   // global expert base for ze=0
  int kcShift; int kcK;        // split-K: z = (ze << kcShift) | kc; k-off = kc*kcK
};

template <int EPI, bool GATHER, bool SWZ>
__launch_bounds__(256, 2)
__global__ void gemm_bt(GemmP p) {
  __shared__ bf16 lds[16384];          // A[128][64] | B[128][64], 32 KiB
  bf16* ldsA = lds;
  bf16* ldsB = lds + 8192;

  const int tid  = threadIdx.x;
  const int lane = tid & 63;
  const int wid  = tid >> 6;
  const int wr   = wid >> 1;   // 2x2 wave grid, each wave owns 64x64
  const int wc   = wid & 1;
  const int z    = blockIdx.z;
  const int kc   = z & ((1 << p.kcShift) - 1);
  const int ze   = z >> p.kcShift;

  int bx = blockIdx.x, by = blockIdx.y;
  if constexpr (SWZ) {
    // physical dispatch order is x-fastest; xcd = lin & 7 (8 XCDs round-robin).
    // remap so each XCD owns a contiguous panel-major chunk (B-panel L2 reuse).
    const int gx = gridDim.x, gy = gridDim.y;
    const int nwg = gx * gy;
    const int lin = by * gx + bx;
    const int q = nwg >> 3, r = nwg & 7;
    const int xcd = lin & 7, loc = lin >> 3;
    const int nid = (xcd < r ? xcd * (q + 1) : r * (q + 1) + (xcd - r) * q) + loc;
    bx = nid / gy; by = nid % gy;   // consecutive nid share bx (same B panel)
  }

  const long am0 = (long)by * 128;
  const long bn0 = (long)bx * 128;

  int cntE = 0;
  const int* il = nullptr;
  if constexpr (GATHER || EPI == EPI_MOE) {
    cntE = p.cnt[p.ebase + ze];
    if (am0 >= cntE) return;  // wave-uniform early exit (before any barrier)
    il = p.idx + (long)(p.ebase + ze) * 2048;
  }

  const long lda = p.lda, ldb = p.ldb;
  const long K = p.K;
  const long kco = (long)kc * p.kcK;

  // staging: tile row = j*32 + wid*8 + (lane>>3); within-row 16B chunk is
  // XOR-swizzled: global chunk (lane&7)^(lane>>3) lands at LDS chunk (lane&7).
  const int sub = (lane & 7) ^ (lane >> 3);
  const int rIn = wid * 8 + (lane >> 3);

  const bf16 *aS[4], *bS[4];
  {
    const bf16* Bb = p.Bh + (long)ze * p.bBS + kco + bn0 * ldb;
    const bf16* Ab = p.Ah + (long)ze * p.aBS + kco + am0 * lda;
#pragma unroll
    for (int j = 0; j < 4; ++j) {
      const int row = j * 32 + rIn;
      bS[j] = Bb + (long)row * ldb + sub * 8;
      if constexpr (GATHER) {
        const int rt = (int)am0 + row;
        const long grow = il[rt < cntE ? rt : 0];
        aS[j] = p.Ah + grow * lda + kco + sub * 8;
      } else {
        aS[j] = Ab + (long)row * lda + sub * 8;
      }
    }
  }
  char* dstA[4];
#pragma unroll
  for (int j = 0; j < 4; ++j)
    dstA[j] = (char*)(void*)lds + (j * 256 + wid * 64) * 16;  // +lane*16 by HW

  f32x4 acc[4][4] = {};

  const int r15 = lane & 15;
  const int kcs = lane >> 4;   // 0..3 -> k-chunk within half
  const int xk  = lane & 7;    // row&7 of this lane's fragment rows

  for (long k0 = 0; k0 < K; k0 += 64) {
    __syncthreads();
#pragma unroll
    for (int j = 0; j < 4; ++j) {
      GLOAD_LDS16(aS[j] + k0, dstA[j]);
      GLOAD_LDS16(bS[j] + k0, dstA[j] + 16384);
    }
    __syncthreads();
#pragma unroll
    for (int h = 0; h < 2; ++h) {
      const int q8 = ((kcs + 4 * h) ^ xk) << 3;   // swizzled k-chunk, elems
      bf16x8 a[4], b[4];
#pragma unroll
      for (int m = 0; m < 4; ++m)
        a[m] = *(const bf16x8*)(ldsA + (wr * 64 + m * 16 + r15) * 64 + q8);
#pragma unroll
      for (int n = 0; n < 4; ++n)
        b[n] = *(const bf16x8*)(ldsB + (wc * 64 + n * 16 + r15) * 64 + q8);
#pragma unroll
      for (int m = 0; m < 4; ++m)
#pragma unroll
        for (int n = 0; n < 4; ++n)
          acc[m][n] = __builtin_amdgcn_mfma_f32_16x16x32_bf16(a[m], b[n], acc[m][n], 0, 0, 0);
    }
  }

  const long N = p.N;

#pragma unroll
  for (int m = 0; m < 4; ++m) {
#pragma unroll
    for (int n = 0; n < 4; ++n) {
      const long col = bn0 + wc * 64 + n * 16 + (lane & 15);
      const float bv = (kc == 0) ? p.bias[(long)ze * p.biasBS + col] : 0.0f;
#pragma unroll
      for (int r = 0; r < 4; ++r) {
        const long row = am0 + wr * 64 + m * 16 + (lane >> 4) * 4 + r;
        float v = acc[m][n][r] + bv;
        if constexpr (EPI == EPI_GELU_SPLIT) {
          // write augmented A' row for the next GEMM: [h | l | h], stride ldo
          float g = gelu_tanh(v);
          bf16 hh = (bf16)g;
          long o = row * (long)p.ldo + col;
          p.outH[o] = hh;
          p.outH[o + N] = (bf16)(g - (float)hh);
          p.outH[o + 2 * N] = hh;
        } else if constexpr (EPI == EPI_RESID) {
          // split-K chunks accumulate into X (which pre-holds resid)
          atomicAdd(p.outF + row * N + col, v);
        } else if constexpr (EPI == EPI_GELU_BF16) {
          long o = (long)ze * p.outBS + row * N + col;
          p.outH[o] = (bf16)gelu_tanh(v);
        } else if constexpr (EPI == EPI_MOE) {
          if (row < cntE) {
            const int tok = il[row];
            const float wgt = p.rwp[(long)tok * 8 + p.ebase + ze];
            atomicAdd(p.outF + (long)tok * N + col, wgt * v);
          }
        } else {  // EPI_BIAS
          p.outF[row * N + col] = v;
        }
      }
    }
  }
}

// ------- transpose fp32 [R][C] -> bf16 [C][R] (AUG: [C][3R] = [h|h|l]) -------
template <bool AUG>
__global__ void transpose_cvt(const float* __restrict__ in, bf16* __restrict__ out,
                              int R, int C, long inBS, long outBS) {
  __shared__ float tile[32][33];
  const float* inp = in + (long)blockIdx.z * inBS;
  const long c0 = (long)blockIdx.x * 32;
  const long r0 = (long)blockIdx.y * 32;
  const int tx = threadIdx.x;  // 32
  const int ty = threadIdx.y;  // 8
#pragma unroll
  for (int i = 0; i < 4; ++i) {
    int r = ty + i * 8;
    tile[r][tx] = inp[(r0 + r) * (long)C + c0 + tx];
  }
  __syncthreads();
  const long ob = (long)blockIdx.z * outBS;
  const long stride = AUG ? 3L * R : (long)R;
#pragma unroll
  for (int i = 0; i < 4; ++i) {
    int c = ty + i * 8;
    float v = tile[tx][c];
    bf16 h = (bf16)v;
    long o = ob + (c0 + c) * stride + r0 + tx;
    out[o] = h;
    if constexpr (AUG) {
      out[o + R] = h;
      out[o + 2 * R] = (bf16)(v - (float)h);
    }
  }
}

// ------------- embedding gather -------------
__global__ void embed_kernel(const int* __restrict__ ids, const float* __restrict__ emb,
                             float* __restrict__ x) {
  const long t = blockIdx.x;
  const int id = ids[t];
  ((float4*)(x + t * 1024))[threadIdx.x] = ((const float4*)(emb + (long)id * 1024))[threadIdx.x];
}

// ------------- LayerNorm -> augmented bf16 [h|l|h] row (stride 3072) -------------
__global__ void ln_aug_kernel(const float* __restrict__ x, const float* __restrict__ sc,
                              const float* __restrict__ bi, bf16* __restrict__ oa) {
  const long t = blockIdx.x;
  const int tid = threadIdx.x;  // 256
  const int lane = tid & 63, wid = tid >> 6;
  float4 a = ((const float4*)(x + t * 1024))[tid];
  float s = a.x + a.y + a.z + a.w;
  float q = a.x * a.x + a.y * a.y + a.z * a.z + a.w * a.w;
#pragma unroll
  for (int off = 32; off; off >>= 1) {
    s += __shfl_down(s, off);
    q += __shfl_down(q, off);
  }
  __shared__ float sr[4], qr[4];
  if (lane == 0) { sr[wid] = s; qr[wid] = q; }
  __syncthreads();
  s = sr[0] + sr[1] + sr[2] + sr[3];
  q = qr[0] + qr[1] + qr[2] + qr[3];
  const float mu = s * (1.0f / 1024.0f);
  const float var = q * (1.0f / 1024.0f) - mu * mu;
  const float rs = rsqrtf(var + 1e-5f);
#pragma unroll
  for (int j = 0; j < 4; ++j) {
    const int d = tid * 4 + j;
    const float g = (((const float*)&a)[j] - mu) * rs * sc[d] + bi[d];
    const bf16 h = (bf16)g;
    oa[t * 3072 + d] = h;
    oa[t * 3072 + 1024 + d] = (bf16)(g - (float)h);
    oa[t * 3072 + 2048 + d] = h;
  }
}

// ------------- router: logits, top-2 softmax, scatter + top2 record -------------
__global__ void router_kernel(const float* __restrict__ x, const float* __restrict__ Wr,
                              const float* __restrict__ br, float* __restrict__ rwo,
                              int* __restrict__ top2) {
  const long t = blockIdx.x;
  const int lane = threadIdx.x;  // 64
  float acc[8];
#pragma unroll
  for (int e = 0; e < 8; ++e) acc[e] = 0.0f;
  const float4* xr = (const float4*)(x + t * 1024);
#pragma unroll
  for (int j = 0; j < 4; ++j) {
    const int d4 = j * 64 + lane;
    float4 xv = xr[d4];
#pragma unroll
    for (int u = 0; u < 4; ++u) {
      const float xs = ((const float*)&xv)[u];
      const float4* wp = (const float4*)(Wr + (long)(d4 * 4 + u) * 8);
      float4 w0 = wp[0], w1 = wp[1];
      acc[0] += xs * w0.x; acc[1] += xs * w0.y; acc[2] += xs * w0.z; acc[3] += xs * w0.w;
      acc[4] += xs * w1.x; acc[5] += xs * w1.y; acc[6] += xs * w1.z; acc[7] += xs * w1.w;
    }
  }
#pragma unroll
  for (int off = 32; off; off >>= 1)
#pragma unroll
    for (int e = 0; e < 8; ++e) acc[e] += __shfl_down(acc[e], off);
  if (lane == 0) {
    float v[8];
#pragma unroll
    for (int e = 0; e < 8; ++e) v[e] = acc[e] + br[e];
    int i0 = 0; float v0 = v[0];
    for (int e = 1; e < 8; ++e) if (v[e] > v0) { v0 = v[e]; i0 = e; }
    int i1 = -1; float v1 = -3.4e38f;
    for (int e = 0; e < 8; ++e) if (e != i0 && v[e] > v1) { v1 = v[e]; i1 = e; }
    float e1 = expf(v1 - v0);
    float den = 1.0f + e1;
    float w0 = 1.0f / den, w1 = e1 / den;
    float* o = rwo + t * 8;
#pragma unroll
    for (int e = 0; e < 8; ++e) o[e] = (e == i0) ? w0 : (e == i1 ? w1 : 0.0f);
    top2[t] = i0 | (i1 << 8);
  }
}

// ------------- per-expert token list build (order-free; outputs order-invariant) ------
__global__ void build_lists(const int* __restrict__ top2, int* __restrict__ cnt,
                            int* __restrict__ idx) {
  const int t = blockIdx.x * 256 + threadIdx.x;
  const int rec = top2[t];
  const int e0 = rec & 255, e1 = (rec >> 8) & 255;
  int p0 = atomicAdd(&cnt[e0], 1);
  idx[e0 * 2048 + p0] = t;
  int p1 = atomicAdd(&cnt[e1], 1);
  idx[e1 * 2048 + p1] = t;
}

// ------------- fp32 -> bf16 flat convert -------------
__global__ void cvt_bf16_kernel(const float* __restrict__ in, bf16* __restrict__ out, long n) {
  long i = ((long)blockIdx.x * blockDim.x + threadIdx.x) * 8;
  if (i >= n) return;
  float4 a = *(const float4*)(in + i);
  float4 b = *(const float4*)(in + i + 4);
  bf16x8 o;
  o[0] = (bf16)a.x; o[1] = (bf16)a.y; o[2] = (bf16)a.z; o[3] = (bf16)a.w;
  o[4] = (bf16)b.x; o[5] = (bf16)b.y; o[6] = (bf16)b.z; o[7] = (bf16)b.w;
  *(bf16x8*)(out + i) = o;
}

// ---------------- host launch ----------------
extern "C" void kernel_launch(void* const* d_in, const int* in_sizes, int n_in,
                              void* d_out, int out_size, void* d_ws, size_t ws_size,
                              hipStream_t stream) {
  (void)in_sizes; (void)n_in; (void)out_size; (void)ws_size;
  const int*   ids  = (const int*)d_in[0];
  const float* emb  = (const float*)d_in[1];
  const float* tlns = (const float*)d_in[2];
  const float* tlnb = (const float*)d_in[3];
  const float* tw1  = (const float*)d_in[4];
  const float* tb1  = (const float*)d_in[5];
  const float* tw2  = (const float*)d_in[6];
  const float* tb2  = (const float*)d_in[7];
  const float* Wr   = (const float*)d_in[8];
  const float* br   = (const float*)d_in[9];
  const float* ew1  = (const float*)d_in[10];
  const float* eb1  = (const float*)d_in[11];
  const float* ew2  = (const float*)d_in[12];
  const float* eb2  = (const float*)d_in[13];
  const float* Wl   = (const float*)d_in[14];
  const float* bl   = (const float*)d_in[15];

  float* logits = (float*)d_out;
  float* rwout  = (float*)d_out + (long)Tm * Vm;

  size_t off = 0;
  auto take = [&](size_t bytes) {
    void* pp = (char*)d_ws + off;
    off += (bytes + 255) & ~(size_t)255;
    return pp;
  };
  float* X    = (float*)take((size_t)Tm * Dm * 4);
  bf16*  XB   = (bf16*) take((size_t)Tm * Dm * 2);
  float* Y    = (float*)take((size_t)Tm * Dm * 4);
  bf16*  YB   = (bf16*) take((size_t)Tm * Dm * 2);
  int*   top2 = (int*)  take((size_t)Tm * 4);
  int*   cnt  = (int*)  take(8 * 4);
  int*   idxl = (int*)  take((size_t)8 * Tm * 4);
  char*  S    = (char*) take(134217728);   // 128 MiB phase-shared scratch

  // temporal phase
  bf16* A1  = (bf16*)S;                              // [2048][3072]  12.6 MB
  bf16* W1A = (bf16*)(S + 12582912);                 // [4096][3072]  25.2 MB
  bf16* W2A = (bf16*)(S + 12582912 + 25165824);      // [1024][12288] 25.2 MB
  bf16* HTA = (bf16*)(S + 12582912 + 2 * 25165824);  // [2048][12288] 50.3 MB
  // expert phase
  bf16* EW1T = (bf16*)S;                             // 4x[4096][1024] 33.6 MB
  bf16* HE   = (bf16*)(S + 33554432);                // 4x[2048][4096] 67.1 MB
  bf16* EW2T = (bf16*)(S + 100663296);               // 4x[1024][4096] 33.6 MB
  // logits phase
  bf16* WLT  = (bf16*)S;                             // [32000][1024]  65.5 MB

  embed_kernel<<<dim3(Tm), dim3(256), 0, stream>>>(ids, emb, X);

  // ---- temporal residual MLP blocks: augmented-K plain GEMMs ----
  for (int l = 0; l < 2; ++l) {
    transpose_cvt<true><<<dim3(DFFm / 32, Dm / 32, 1), dim3(32, 8), 0, stream>>>(
        tw1 + (long)l * Dm * DFFm, W1A, Dm, DFFm, 0, 0);
    transpose_cvt<true><<<dim3(Dm / 32, DFFm / 32, 1), dim3(32, 8), 0, stream>>>(
        tw2 + (long)l * DFFm * Dm, W2A, DFFm, Dm, 0, 0);
    ln_aug_kernel<<<dim3(Tm), dim3(256), 0, stream>>>(X, tlns + l * Dm, tlnb + l * Dm, A1);

    GemmP p1{};
    p1.Ah = A1; p1.Bh = W1A;
    p1.bias = tb1 + (long)l * DFFm;
    p1.outH = HTA;
    p1.K = 3072; p1.N = DFFm; p1.lda = 3072; p1.ldb = 3072; p1.ldo = 3 * DFFm;
    gemm_bt<EPI_GELU_SPLIT, false, true>
        <<<dim3(DFFm / 128, Tm / 128, 1), dim3(256), 0, stream>>>(p1);

    // split-K z=8 (kcShift=3, chunks of 1536): 1024 blocks, 4/CU
    GemmP p2{};
    p2.Ah = HTA; p2.Bh = W2A;
    p2.bias = tb2 + (long)l * Dm;
    p2.outF = X;                         // X pre-holds residual; chunks atomicAdd
    p2.K = 1536; p2.N = Dm; p2.lda = 12288; p2.ldb = 12288;
    p2.kcShift = 3; p2.kcK = 1536;
    gemm_bt<EPI_RESID, false, true>
        <<<dim3(Dm / 128, Tm / 128, 8), dim3(256), 0, stream>>>(p2);
  }

  // ---- router (fp32) + token lists ----
  router_kernel<<<dim3(Tm), dim3(64), 0, stream>>>(X, Wr, br, rwout, top2);
  hipMemsetAsync(cnt, 0, 8 * 4, stream);
  build_lists<<<dim3(Tm / 256), dim3(256), 0, stream>>>(top2, cnt, idxl);
  cvt_bf16_kernel<<<dim3(Tm * Dm / (256 * 8)), dim3(256), 0, stream>>>(X, XB, (long)Tm * Dm);
  hipMemsetAsync(Y, 0, (size_t)Tm * Dm * 4, stream);

  // ---- sparse top-2 expert stack, 2 quads of 4 experts (bf16) ----
  for (int q = 0; q < 2; ++q) {
    transpose_cvt<false><<<dim3(DFFm / 32, Dm / 32, 4), dim3(32, 8), 0, stream>>>(
        ew1 + (long)q * 4 * Dm * DFFm, EW1T, Dm, DFFm, (long)Dm * DFFm, (long)DFFm * Dm);
    transpose_cvt<false><<<dim3(Dm / 32, DFFm / 32, 4), dim3(32, 8), 0, stream>>>(
        ew2 + (long)q * 4 * DFFm * Dm, EW2T, DFFm, Dm, (long)DFFm * Dm, (long)Dm * DFFm);

    GemmP pe1{};
    pe1.Ah = XB; pe1.Bh = EW1T;
    pe1.bias = eb1 + (long)q * 4 * DFFm; pe1.biasBS = DFFm;
    pe1.outH = HE; pe1.outBS = (long)Tm * DFFm;
    pe1.aBS = 0; pe1.bBS = (long)DFFm * Dm;
    pe1.cnt = cnt; pe1.idx = idxl; pe1.ebase = q * 4;
    pe1.K = Dm; pe1.N = DFFm; pe1.lda = Dm; pe1.ldb = Dm;
    gemm_bt<EPI_GELU_BF16, true, true>
        <<<dim3(DFFm / 128, Tm / 128, 4), dim3(256), 0, stream>>>(pe1);

    // split-K x4 per expert: z = (e<<2)|kc, chunks of 1024: ~512 active blocks
    GemmP pe2{};
    pe2.Ah = HE; pe2.aBS = (long)Tm * DFFm;
    pe2.Bh = EW2T; pe2.bBS = (long)Dm * DFFm;
    pe2.bias = eb2 + (long)q * 4 * Dm; pe2.biasBS = Dm;
    pe2.rwp = rwout; pe2.cnt = cnt; pe2.idx = idxl; pe2.ebase = q * 4;
    pe2.outF = Y;
    pe2.K = 1024; pe2.N = Dm; pe2.lda = DFFm; pe2.ldb = DFFm;
    pe2.kcShift = 2; pe2.kcK = 1024;
    gemm_bt<EPI_MOE, false, true>
        <<<dim3(Dm / 128, Tm / 128, 16), dim3(256), 0, stream>>>(pe2);
  }

  // ---- final logits GEMM ----
  cvt_bf16_kernel<<<dim3(Tm * Dm / (256 * 8)), dim3(256), 0, stream>>>(Y, YB, (long)Tm * Dm);
  transpose_cvt<false><<<dim3(Vm / 32, Dm / 32, 1), dim3(32, 8), 0, stream>>>(
      Wl, WLT, Dm, Vm, 0, 0);
  GemmP pl{};
  pl.Ah = YB; pl.Bh = WLT; pl.bias = bl;
  pl.outF = logits;
  pl.K = Dm; pl.N = Vm; pl.lda = Dm; pl.ldb = Dm;
  gemm_bt<EPI_BIAS, false, true>
      <<<dim3(Vm / 128, Tm / 128, 1), dim3(256), 0, stream>>>(pl);
}

// Round 5
// 980.506 us; speedup vs baseline: 1.2157x; 1.0268x over previous
//
#include <hip/hip_runtime.h>
#include <stdint.h>

typedef __bf16 bf16;
typedef __bf16 bf16x8 __attribute__((ext_vector_type(8)));
typedef float f32x4 __attribute__((ext_vector_type(4)));

#define DEV __device__ __forceinline__

static constexpr int Dm   = 1024;
static constexpr int DFFm = 4096;
static constexpr int Tm   = 2048;   // B*S tokens
static constexpr int Vm   = 32000;

// ---------------- helpers ----------------
#define GLOAD_LDS16(g, l)                                                      \
  __builtin_amdgcn_global_load_lds(                                            \
      (const __attribute__((address_space(1))) unsigned int*)(g),              \
      (__attribute__((address_space(3))) unsigned int*)(l), 16, 0, 0)

DEV float gelu_tanh(float v) {  // matches jax.nn.gelu (approximate=True)
  float u = 0.7978845608028654f * (v + 0.044715f * v * v * v);
  float e = __expf(2.0f * u);
  float t = 1.0f - 2.0f / (e + 1.0f);
  return 0.5f * v * (1.0f + t);
}

// ---------------- GEMM: C = A[M][K] * B^T ([N][K]) ----------------
// Augmented-K fp32-ish accuracy: A'=[Ah|Al|Ah], B'=[Bh|Bh|Bl] -> hh+lh+hl.
// BK=64, XOR-swizzled LDS (chunk ^= row&7) with pre-swizzled global source.
enum { EPI_GELU_SPLIT = 0, EPI_RESID = 1, EPI_GELU_BF16 = 2, EPI_MOE = 3, EPI_BIAS = 4 };

struct GemmP {
  const bf16* Ah;
  const bf16* Bh;
  const float* bias;
  const float* rwp;     // routing weights [T][8]
  const int* cnt;       // per-expert token counts [8]
  const int* idx;       // per-expert token lists [8][2048]
  float* outF;
  bf16* outH;
  int K; int N;
  int lda; int ldb; int ldo;
  long aBS, bBS, outBS;        // per-ze strides
  int biasBS;
  int ebase;                   // global expert base for ze=0
  int kcShift; int kcK;        // split-K: z = (ze << kcShift) | kc; k-off = kc*kcK
};

template <int EPI, bool GATHER, bool SWZ>
__launch_bounds__(256, 2)
__global__ void gemm_bt(GemmP p) {
  __shared__ bf16 lds[16384];          // A[128][64] | B[128][64], 32 KiB
  bf16* ldsA = lds;
  bf16* ldsB = lds + 8192;

  const int tid  = threadIdx.x;
  const int lane = tid & 63;
  const int wid  = tid >> 6;
  const int wr   = wid >> 1;   // 2x2 wave grid, each wave owns 64x64
  const int wc   = wid & 1;
  const int z    = blockIdx.z;
  const int kc   = z & ((1 << p.kcShift) - 1);
  const int ze   = z >> p.kcShift;

  int bx = blockIdx.x, by = blockIdx.y;
  if constexpr (SWZ) {
    // physical dispatch order is x-fastest; xcd = lin & 7 (8 XCDs round-robin).
    const int gx = gridDim.x, gy = gridDim.y;
    const int nwg = gx * gy;
    const int lin = by * gx + bx;
    const int q = nwg >> 3, r = nwg & 7;
    const int xcd = lin & 7, loc = lin >> 3;
    const int nid = (xcd < r ? xcd * (q + 1) : r * (q + 1) + (xcd - r) * q) + loc;
    bx = nid / gy; by = nid % gy;   // consecutive nid share bx (same B panel)
  }

  const long am0 = (long)by * 128;
  const long bn0 = (long)bx * 128;

  int cntE = 0;
  const int* il = nullptr;
  if constexpr (GATHER || EPI == EPI_MOE) {
    cntE = p.cnt[p.ebase + ze];
    if (am0 >= cntE) return;  // wave-uniform early exit (before any barrier)
    il = p.idx + (long)(p.ebase + ze) * 2048;
  }

  const long lda = p.lda, ldb = p.ldb;
  const long K = p.K;
  const long kco = (long)kc * p.kcK;

  // staging: tile row = j*32 + wid*8 + (lane>>3); within-row 16B chunk is
  // XOR-swizzled: global chunk (lane&7)^(lane>>3) lands at LDS chunk (lane&7).
  const int sub = (lane & 7) ^ (lane >> 3);
  const int rIn = wid * 8 + (lane >> 3);

  const bf16 *aS[4], *bS[4];
  {
    const bf16* Bb = p.Bh + (long)ze * p.bBS + kco + bn0 * ldb;
    const bf16* Ab = p.Ah + (long)ze * p.aBS + kco + am0 * lda;
#pragma unroll
    for (int j = 0; j < 4; ++j) {
      const int row = j * 32 + rIn;
      bS[j] = Bb + (long)row * ldb + sub * 8;
      if constexpr (GATHER) {
        const int rt = (int)am0 + row;
        const long grow = il[rt < cntE ? rt : 0];
        aS[j] = p.Ah + grow * lda + kco + sub * 8;
      } else {
        aS[j] = Ab + (long)row * lda + sub * 8;
      }
    }
  }
  char* dstA[4];
#pragma unroll
  for (int j = 0; j < 4; ++j)
    dstA[j] = (char*)(void*)lds + (j * 256 + wid * 64) * 16;  // +lane*16 by HW

  f32x4 acc[4][4] = {};

  const int r15 = lane & 15;
  const int kcs = lane >> 4;   // 0..3 -> k-chunk within half
  const int xk  = lane & 7;    // row&7 of this lane's fragment rows

  for (long k0 = 0; k0 < K; k0 += 64) {
    __syncthreads();
#pragma unroll
    for (int j = 0; j < 4; ++j) {
      GLOAD_LDS16(aS[j] + k0, dstA[j]);
      GLOAD_LDS16(bS[j] + k0, dstA[j] + 16384);
    }
    __syncthreads();
#pragma unroll
    for (int h = 0; h < 2; ++h) {
      const int q8 = ((kcs + 4 * h) ^ xk) << 3;   // swizzled k-chunk, elems
      bf16x8 a[4], b[4];
#pragma unroll
      for (int m = 0; m < 4; ++m)
        a[m] = *(const bf16x8*)(ldsA + (wr * 64 + m * 16 + r15) * 64 + q8);
#pragma unroll
      for (int n = 0; n < 4; ++n)
        b[n] = *(const bf16x8*)(ldsB + (wc * 64 + n * 16 + r15) * 64 + q8);
#pragma unroll
      for (int m = 0; m < 4; ++m)
#pragma unroll
        for (int n = 0; n < 4; ++n)
          acc[m][n] = __builtin_amdgcn_mfma_f32_16x16x32_bf16(a[m], b[n], acc[m][n], 0, 0, 0);
    }
  }

  const long N = p.N;

#pragma unroll
  for (int m = 0; m < 4; ++m) {
#pragma unroll
    for (int n = 0; n < 4; ++n) {
      const long col = bn0 + wc * 64 + n * 16 + (lane & 15);
      const float bv = (kc == 0) ? p.bias[(long)ze * p.biasBS + col] : 0.0f;
#pragma unroll
      for (int r = 0; r < 4; ++r) {
        const long row = am0 + wr * 64 + m * 16 + (lane >> 4) * 4 + r;
        float v = acc[m][n][r] + bv;
        if constexpr (EPI == EPI_GELU_SPLIT) {
          float g = gelu_tanh(v);
          bf16 hh = (bf16)g;
          long o = row * (long)p.ldo + col;
          p.outH[o] = hh;
          p.outH[o + N] = (bf16)(g - (float)hh);
          p.outH[o + 2 * N] = hh;
        } else if constexpr (EPI == EPI_RESID) {
          atomicAdd(p.outF + row * N + col, v);
        } else if constexpr (EPI == EPI_GELU_BF16) {
          long o = (long)ze * p.outBS + row * N + col;
          p.outH[o] = (bf16)gelu_tanh(v);
        } else if constexpr (EPI == EPI_MOE) {
          if (row < cntE) {
            const int tok = il[row];
            const float wgt = p.rwp[(long)tok * 8 + p.ebase + ze];
            atomicAdd(p.outF + (long)tok * N + col, wgt * v);
          }
        } else {  // EPI_BIAS
          p.outF[row * N + col] = v;
        }
      }
    }
  }
}

// -------- 256x256-tile / 8-wave GEMM, counted-vmcnt pipeline (logits) --------
// C[M][N] = A[M][K] * B^T ([N][K]) + bias. Raw s_barrier + vmcnt(8): staging
// loads for tile kt+2 stay in flight across barriers (T3/T4), T2 swizzle, T5.
template <bool SWZ>
__launch_bounds__(512, 2)
__global__ void gemm256_bias(const bf16* __restrict__ A, const bf16* __restrict__ B,
                             const float* __restrict__ bias, float* __restrict__ out,
                             int Kc, int Nc) {
  __shared__ bf16 lds[65536];   // 128 KiB: buf{0,1} x (A[256][64] | B[256][64])

  const int tid  = threadIdx.x;
  const int lane = tid & 63;
  const int wid  = tid >> 6;     // 8 waves: wr = wid>>2 (2), wc = wid&3 (4)
  const int wr   = wid >> 2;
  const int wc   = wid & 3;

  int bx = blockIdx.x, by = blockIdx.y;
  if constexpr (SWZ) {
    const int gx = gridDim.x, gy = gridDim.y;
    const int nwg = gx * gy;
    const int lin = by * gx + bx;
    const int q = nwg >> 3, r = nwg & 7;
    const int xcd = lin & 7, loc = lin >> 3;
    const int nid = (xcd < r ? xcd * (q + 1) : r * (q + 1) + (xcd - r) * q) + loc;
    bx = nid / gy; by = nid % gy;
  }
  const long am0 = (long)by * 256;
  const long bn0 = (long)bx * 256;
  const long K = Kc;
  const int NT = Kc >> 6;        // K-tiles of 64

  // staging geometry: per thread 4 A-loads + 4 B-loads per K-tile.
  // tile row = j*64 + wid*8 + (lane>>3); global chunk sub = (lane&7)^(lane>>3)
  // lands at LDS chunk lane&7 (XOR row-swizzle, dest linear per wave).
  const int sub = (lane & 7) ^ (lane >> 3);
  const int rw  = wid * 8 + (lane >> 3);
  const bf16 *aS[4], *bS[4];
#pragma unroll
  for (int j = 0; j < 4; ++j) {
    const int row = j * 64 + rw;
    aS[j] = A + (am0 + row) * K + sub * 8;
    bS[j] = B + (bn0 + row) * K + sub * 8;
  }

  f32x4 acc[8][4] = {};
  const int r15 = lane & 15;
  const int kcs = lane >> 4;
  const int xk  = lane & 7;

  // stage one K-tile (A+B) into buffer `buf`
  auto stage = [&](int kt, int buf) {
    const long ko = (long)kt * 64;
    char* base = (char*)(void*)lds + buf * 65536;
#pragma unroll
    for (int j = 0; j < 4; ++j) {
      char* d = base + (j * 64 + wid * 8) * 128;   // +lane*16 by HW
      GLOAD_LDS16(aS[j] + ko, d);
      GLOAD_LDS16(bS[j] + ko, d + 32768);
    }
  };

  stage(0, 0);
  stage(1, 1);

  for (int kt = 0; kt < NT; ++kt) {
    const int cur = kt & 1;
    if (kt < NT - 1) asm volatile("s_waitcnt vmcnt(8)" ::: "memory");
    else             asm volatile("s_waitcnt vmcnt(0)" ::: "memory");
    __builtin_amdgcn_s_barrier();

    const bf16* LA = lds + cur * 32768;
    const bf16* LB = LA + 16384;

    // k-half 0 frags + MFMA
    bf16x8 a0[8], b0[4];
    {
      const int q8 = (kcs ^ xk) << 3;
#pragma unroll
      for (int m = 0; m < 8; ++m)
        a0[m] = *(const bf16x8*)(LA + (wr * 128 + m * 16 + r15) * 64 + q8);
#pragma unroll
      for (int n = 0; n < 4; ++n)
        b0[n] = *(const bf16x8*)(LB + (wc * 64 + n * 16 + r15) * 64 + q8);
    }
    __builtin_amdgcn_s_setprio(1);
#pragma unroll
    for (int m = 0; m < 8; ++m)
#pragma unroll
      for (int n = 0; n < 4; ++n)
        acc[m][n] = __builtin_amdgcn_mfma_f32_16x16x32_bf16(a0[m], b0[n], acc[m][n], 0, 0, 0);
    __builtin_amdgcn_s_setprio(0);

    // k-half 1 frags
    bf16x8 a1[8], b1[4];
    {
      const int q8 = ((kcs + 4) ^ xk) << 3;
#pragma unroll
      for (int m = 0; m < 8; ++m)
        a1[m] = *(const bf16x8*)(LA + (wr * 128 + m * 16 + r15) * 64 + q8);
#pragma unroll
      for (int n = 0; n < 4; ++n)
        b1[n] = *(const bf16x8*)(LB + (wc * 64 + n * 16 + r15) * 64 + q8);
    }
    // all reads of buf[cur] complete before any wave overwrites it
    asm volatile("s_waitcnt lgkmcnt(0)" ::: "memory");
    __builtin_amdgcn_s_barrier();
    if (kt + 2 < NT) stage(kt + 2, cur);

    __builtin_amdgcn_s_setprio(1);
#pragma unroll
    for (int m = 0; m < 8; ++m)
#pragma unroll
      for (int n = 0; n < 4; ++n)
        acc[m][n] = __builtin_amdgcn_mfma_f32_16x16x32_bf16(a1[m], b1[n], acc[m][n], 0, 0, 0);
    __builtin_amdgcn_s_setprio(0);
  }

  const long N = Nc;
#pragma unroll
  for (int m = 0; m < 8; ++m) {
#pragma unroll
    for (int n = 0; n < 4; ++n) {
      const long col = bn0 + wc * 64 + n * 16 + r15;
      const float bv = bias[col];
#pragma unroll
      for (int r = 0; r < 4; ++r) {
        const long row = am0 + wr * 128 + m * 16 + (lane >> 4) * 4 + r;
        out[row * N + col] = acc[m][n][r] + bv;
      }
    }
  }
}

// ------- transpose fp32 [R][C] -> bf16 [C][R] (AUG: [C][3R] = [h|h|l]) -------
template <bool AUG>
__global__ void transpose_cvt(const float* __restrict__ in, bf16* __restrict__ out,
                              int R, int C, long inBS, long outBS) {
  __shared__ float tile[32][33];
  const float* inp = in + (long)blockIdx.z * inBS;
  const long c0 = (long)blockIdx.x * 32;
  const long r0 = (long)blockIdx.y * 32;
  const int tx = threadIdx.x;  // 32
  const int ty = threadIdx.y;  // 8
#pragma unroll
  for (int i = 0; i < 4; ++i) {
    int r = ty + i * 8;
    tile[r][tx] = inp[(r0 + r) * (long)C + c0 + tx];
  }
  __syncthreads();
  const long ob = (long)blockIdx.z * outBS;
  const long stride = AUG ? 3L * R : (long)R;
#pragma unroll
  for (int i = 0; i < 4; ++i) {
    int c = ty + i * 8;
    float v = tile[tx][c];
    bf16 h = (bf16)v;
    long o = ob + (c0 + c) * stride + r0 + tx;
    out[o] = h;
    if constexpr (AUG) {
      out[o + R] = h;
      out[o + 2 * R] = (bf16)(v - (float)h);
    }
  }
}

// ------------- embedding gather -------------
__global__ void embed_kernel(const int* __restrict__ ids, const float* __restrict__ emb,
                             float* __restrict__ x) {
  const long t = blockIdx.x;
  const int id = ids[t];
  ((float4*)(x + t * 1024))[threadIdx.x] = ((const float4*)(emb + (long)id * 1024))[threadIdx.x];
}

// ------------- LayerNorm -> augmented bf16 [h|l|h] row (stride 3072) -------------
__global__ void ln_aug_kernel(const float* __restrict__ x, const float* __restrict__ sc,
                              const float* __restrict__ bi, bf16* __restrict__ oa) {
  const long t = blockIdx.x;
  const int tid = threadIdx.x;  // 256
  const int lane = tid & 63, wid = tid >> 6;
  float4 a = ((const float4*)(x + t * 1024))[tid];
  float s = a.x + a.y + a.z + a.w;
  float q = a.x * a.x + a.y * a.y + a.z * a.z + a.w * a.w;
#pragma unroll
  for (int off = 32; off; off >>= 1) {
    s += __shfl_down(s, off);
    q += __shfl_down(q, off);
  }
  __shared__ float sr[4], qr[4];
  if (lane == 0) { sr[wid] = s; qr[wid] = q; }
  __syncthreads();
  s = sr[0] + sr[1] + sr[2] + sr[3];
  q = qr[0] + qr[1] + qr[2] + qr[3];
  const float mu = s * (1.0f / 1024.0f);
  const float var = q * (1.0f / 1024.0f) - mu * mu;
  const float rs = rsqrtf(var + 1e-5f);
#pragma unroll
  for (int j = 0; j < 4; ++j) {
    const int d = tid * 4 + j;
    const float g = (((const float*)&a)[j] - mu) * rs * sc[d] + bi[d];
    const bf16 h = (bf16)g;
    oa[t * 3072 + d] = h;
    oa[t * 3072 + 1024 + d] = (bf16)(g - (float)h);
    oa[t * 3072 + 2048 + d] = h;
  }
}

// ------------- router: logits, top-2 softmax, scatter + top2 record -------------
__global__ void router_kernel(const float* __restrict__ x, const float* __restrict__ Wr,
                              const float* __restrict__ br, float* __restrict__ rwo,
                              int* __restrict__ top2) {
  const long t = blockIdx.x;
  const int lane = threadIdx.x;  // 64
  float acc[8];
#pragma unroll
  for (int e = 0; e < 8; ++e) acc[e] = 0.0f;
  const float4* xr = (const float4*)(x + t * 1024);
#pragma unroll
  for (int j = 0; j < 4; ++j) {
    const int d4 = j * 64 + lane;
    float4 xv = xr[d4];
#pragma unroll
    for (int u = 0; u < 4; ++u) {
      const float xs = ((const float*)&xv)[u];
      const float4* wp = (const float4*)(Wr + (long)(d4 * 4 + u) * 8);
      float4 w0 = wp[0], w1 = wp[1];
      acc[0] += xs * w0.x; acc[1] += xs * w0.y; acc[2] += xs * w0.z; acc[3] += xs * w0.w;
      acc[4] += xs * w1.x; acc[5] += xs * w1.y; acc[6] += xs * w1.z; acc[7] += xs * w1.w;
    }
  }
#pragma unroll
  for (int off = 32; off; off >>= 1)
#pragma unroll
    for (int e = 0; e < 8; ++e) acc[e] += __shfl_down(acc[e], off);
  if (lane == 0) {
    float v[8];
#pragma unroll
    for (int e = 0; e < 8; ++e) v[e] = acc[e] + br[e];
    int i0 = 0; float v0 = v[0];
    for (int e = 1; e < 8; ++e) if (v[e] > v0) { v0 = v[e]; i0 = e; }
    int i1 = -1; float v1 = -3.4e38f;
    for (int e = 0; e < 8; ++e) if (e != i0 && v[e] > v1) { v1 = v[e]; i1 = e; }
    float e1 = expf(v1 - v0);
    float den = 1.0f + e1;
    float w0 = 1.0f / den, w1 = e1 / den;
    float* o = rwo + t * 8;
#pragma unroll
    for (int e = 0; e < 8; ++e) o[e] = (e == i0) ? w0 : (e == i1 ? w1 : 0.0f);
    top2[t] = i0 | (i1 << 8);
  }
}

// ------------- per-expert token list build (order-free; outputs order-invariant) ------
__global__ void build_lists(const int* __restrict__ top2, int* __restrict__ cnt,
                            int* __restrict__ idx) {
  const int t = blockIdx.x * 256 + threadIdx.x;
  const int rec = top2[t];
  const int e0 = rec & 255, e1 = (rec >> 8) & 255;
  int p0 = atomicAdd(&cnt[e0], 1);
  idx[e0 * 2048 + p0] = t;
  int p1 = atomicAdd(&cnt[e1], 1);
  idx[e1 * 2048 + p1] = t;
}

// ------------- fp32 -> bf16 flat convert -------------
__global__ void cvt_bf16_kernel(const float* __restrict__ in, bf16* __restrict__ out, long n) {
  long i = ((long)blockIdx.x * blockDim.x + threadIdx.x) * 8;
  if (i >= n) return;
  float4 a = *(const float4*)(in + i);
  float4 b = *(const float4*)(in + i + 4);
  bf16x8 o;
  o[0] = (bf16)a.x; o[1] = (bf16)a.y; o[2] = (bf16)a.z; o[3] = (bf16)a.w;
  o[4] = (bf16)b.x; o[5] = (bf16)b.y; o[6] = (bf16)b.z; o[7] = (bf16)b.w;
  *(bf16x8*)(out + i) = o;
}

// ---------------- host launch ----------------
extern "C" void kernel_launch(void* const* d_in, const int* in_sizes, int n_in,
                              void* d_out, int out_size, void* d_ws, size_t ws_size,
                              hipStream_t stream) {
  (void)in_sizes; (void)n_in; (void)out_size; (void)ws_size;
  const int*   ids  = (const int*)d_in[0];
  const float* emb  = (const float*)d_in[1];
  const float* tlns = (const float*)d_in[2];
  const float* tlnb = (const float*)d_in[3];
  const float* tw1  = (const float*)d_in[4];
  const float* tb1  = (const float*)d_in[5];
  const float* tw2  = (const float*)d_in[6];
  const float* tb2  = (const float*)d_in[7];
  const float* Wr   = (const float*)d_in[8];
  const float* br   = (const float*)d_in[9];
  const float* ew1  = (const float*)d_in[10];
  const float* eb1  = (const float*)d_in[11];
  const float* ew2  = (const float*)d_in[12];
  const float* eb2  = (const float*)d_in[13];
  const float* Wl   = (const float*)d_in[14];
  const float* bl   = (const float*)d_in[15];

  float* logits = (float*)d_out;
  float* rwout  = (float*)d_out + (long)Tm * Vm;

  size_t off = 0;
  auto take = [&](size_t bytes) {
    void* pp = (char*)d_ws + off;
    off += (bytes + 255) & ~(size_t)255;
    return pp;
  };
  float* X    = (float*)take((size_t)Tm * Dm * 4);
  bf16*  XB   = (bf16*) take((size_t)Tm * Dm * 2);
  float* Y    = (float*)take((size_t)Tm * Dm * 4);
  bf16*  YB   = (bf16*) take((size_t)Tm * Dm * 2);
  int*   top2 = (int*)  take((size_t)Tm * 4);
  int*   cnt  = (int*)  take(8 * 4);
  int*   idxl = (int*)  take((size_t)8 * Tm * 4);
  char*  S    = (char*) take(134217728);   // 128 MiB phase-shared scratch

  // temporal phase
  bf16* A1  = (bf16*)S;                              // [2048][3072]  12.6 MB
  bf16* W1A = (bf16*)(S + 12582912);                 // [4096][3072]  25.2 MB
  bf16* W2A = (bf16*)(S + 12582912 + 25165824);      // [1024][12288] 25.2 MB
  bf16* HTA = (bf16*)(S + 12582912 + 2 * 25165824);  // [2048][12288] 50.3 MB
  // expert phase
  bf16* EW1T = (bf16*)S;                             // 4x[4096][1024] 33.6 MB
  bf16* HE   = (bf16*)(S + 33554432);                // 4x[2048][4096] 67.1 MB
  bf16* EW2T = (bf16*)(S + 100663296);               // 4x[1024][4096] 33.6 MB
  // logits phase
  bf16* WLT  = (bf16*)S;                             // [32000][1024]  65.5 MB

  embed_kernel<<<dim3(Tm), dim3(256), 0, stream>>>(ids, emb, X);

  // ---- temporal residual MLP blocks: augmented-K plain GEMMs ----
  for (int l = 0; l < 2; ++l) {
    transpose_cvt<true><<<dim3(DFFm / 32, Dm / 32, 1), dim3(32, 8), 0, stream>>>(
        tw1 + (long)l * Dm * DFFm, W1A, Dm, DFFm, 0, 0);
    transpose_cvt<true><<<dim3(Dm / 32, DFFm / 32, 1), dim3(32, 8), 0, stream>>>(
        tw2 + (long)l * DFFm * Dm, W2A, DFFm, Dm, 0, 0);
    ln_aug_kernel<<<dim3(Tm), dim3(256), 0, stream>>>(X, tlns + l * Dm, tlnb + l * Dm, A1);

    GemmP p1{};
    p1.Ah = A1; p1.Bh = W1A;
    p1.bias = tb1 + (long)l * DFFm;
    p1.outH = HTA;
    p1.K = 3072; p1.N = DFFm; p1.lda = 3072; p1.ldb = 3072; p1.ldo = 3 * DFFm;
    gemm_bt<EPI_GELU_SPLIT, false, true>
        <<<dim3(DFFm / 128, Tm / 128, 1), dim3(256), 0, stream>>>(p1);

    // split-K z=8 (kcShift=3, chunks of 1536): 1024 blocks, 4/CU
    GemmP p2{};
    p2.Ah = HTA; p2.Bh = W2A;
    p2.bias = tb2 + (long)l * Dm;
    p2.outF = X;                         // X pre-holds residual; chunks atomicAdd
    p2.K = 1536; p2.N = Dm; p2.lda = 12288; p2.ldb = 12288;
    p2.kcShift = 3; p2.kcK = 1536;
    gemm_bt<EPI_RESID, false, true>
        <<<dim3(Dm / 128, Tm / 128, 8), dim3(256), 0, stream>>>(p2);
  }

  // ---- router (fp32) + token lists ----
  router_kernel<<<dim3(Tm), dim3(64), 0, stream>>>(X, Wr, br, rwout, top2);
  hipMemsetAsync(cnt, 0, 8 * 4, stream);
  build_lists<<<dim3(Tm / 256), dim3(256), 0, stream>>>(top2, cnt, idxl);
  cvt_bf16_kernel<<<dim3(Tm * Dm / (256 * 8)), dim3(256), 0, stream>>>(X, XB, (long)Tm * Dm);
  hipMemsetAsync(Y, 0, (size_t)Tm * Dm * 4, stream);

  // ---- sparse top-2 expert stack, 2 quads of 4 experts (bf16) ----
  for (int q = 0; q < 2; ++q) {
    transpose_cvt<false><<<dim3(DFFm / 32, Dm / 32, 4), dim3(32, 8), 0, stream>>>(
        ew1 + (long)q * 4 * Dm * DFFm, EW1T, Dm, DFFm, (long)Dm * DFFm, (long)DFFm * Dm);
    transpose_cvt<false><<<dim3(Dm / 32, DFFm / 32, 4), dim3(32, 8), 0, stream>>>(
        ew2 + (long)q * 4 * DFFm * Dm, EW2T, DFFm, Dm, (long)DFFm * Dm, (long)Dm * DFFm);

    GemmP pe1{};
    pe1.Ah = XB; pe1.Bh = EW1T;
    pe1.bias = eb1 + (long)q * 4 * DFFm; pe1.biasBS = DFFm;
    pe1.outH = HE; pe1.outBS = (long)Tm * DFFm;
    pe1.aBS = 0; pe1.bBS = (long)DFFm * Dm;
    pe1.cnt = cnt; pe1.idx = idxl; pe1.ebase = q * 4;
    pe1.K = Dm; pe1.N = DFFm; pe1.lda = Dm; pe1.ldb = Dm;
    gemm_bt<EPI_GELU_BF16, true, true>
        <<<dim3(DFFm / 128, Tm / 128, 4), dim3(256), 0, stream>>>(pe1);

    // split-K x4 per expert: z = (e<<2)|kc, chunks of 1024
    GemmP pe2{};
    pe2.Ah = HE; pe2.aBS = (long)Tm * DFFm;
    pe2.Bh = EW2T; pe2.bBS = (long)Dm * DFFm;
    pe2.bias = eb2 + (long)q * 4 * Dm; pe2.biasBS = Dm;
    pe2.rwp = rwout; pe2.cnt = cnt; pe2.idx = idxl; pe2.ebase = q * 4;
    pe2.outF = Y;
    pe2.K = 1024; pe2.N = Dm; pe2.lda = DFFm; pe2.ldb = DFFm;
    pe2.kcShift = 2; pe2.kcK = 1024;
    gemm_bt<EPI_MOE, false, true>
        <<<dim3(Dm / 128, Tm / 128, 16), dim3(256), 0, stream>>>(pe2);
  }

  // ---- final logits GEMM: 256^2 8-wave counted-vmcnt pipeline ----
  cvt_bf16_kernel<<<dim3(Tm * Dm / (256 * 8)), dim3(256), 0, stream>>>(Y, YB, (long)Tm * Dm);
  transpose_cvt<false><<<dim3(Vm / 32, Dm / 32, 1), dim3(32, 8), 0, stream>>>(
      Wl, WLT, Dm, Vm, 0, 0);
  gemm256_bias<true><<<dim3(Vm / 256, Tm / 256, 1), dim3(512), 0, stream>>>(
      YB, WLT, bl, logits, Dm, Vm);
}